// Round 5
// baseline (4866.247 us; speedup 1.0000x reference)
//
#include <hip/hip_runtime.h>

// GRU: B=64, T=2048, D=256, U=256.
//  k0: transpose weights -> bf16 [col][k]
//  k1: proj GEMM -> recurrence-native x layout:
//      XA[t][g][w][lane] = 4 uint4: slots 0-1 = xz[16] (bn 0..3), slots 2-3 = xr[16] (bn 4..7)
//      XB[t][g][w][lane] = 2 uint4: xh[16]  (bn 8..11)
//  k2: recurrence, 4 blocks x 256 thr (4 waves, 1 wave/SIMD). Wave w owns unit
//      cols [w*64,(w+1)*64) for z,r,h. Uz+Ur in 256 AGPRs (inline-asm MFMA with
//      "a" operands -> no accvgpr_read storm, the R4 bottleneck), Uh in 128
//      VGPRs (builtin MFMA). h/v fragments round-trip LDS. Custom barrier
//      (lgkmcnt-only) keeps x prefetch loads in flight across s_barrier.

#define TB 2048
#define NU 256
#define G3 768

typedef __attribute__((ext_vector_type(8))) short bf16x8;
typedef __attribute__((ext_vector_type(4))) float f32x4;

__device__ inline unsigned short f2bf(float f){
  union{float f; unsigned u;} v; v.f = f;
  unsigned r = v.u + 0x7fffu + ((v.u >> 16) & 1u);   // RNE
  return (unsigned short)(r >> 16);
}
__device__ inline unsigned pk2(float a, float b){
  return (unsigned)f2bf(a) | ((unsigned)f2bf(b) << 16);
}
__device__ inline float bflo(unsigned u){
  union{unsigned u; float f;} v; v.u = u << 16; return v.f;
}
__device__ inline float bfhi(unsigned u){
  union{unsigned u; float f;} v; v.u = u & 0xffff0000u; return v.f;
}

// MFMA with B operand in AGPR (direct read, no copy)
#define MFMA_AG(acc, va, ub) \
  asm volatile("v_mfma_f32_16x16x32_bf16 %0, %1, %2, %0" : "+v"(acc) : "v"(va), "a"(ub))
// barrier that drains only LDS (keeps global prefetch in flight)
#define BAR() asm volatile("s_waitcnt lgkmcnt(0)\n\ts_barrier" ::: "memory")

// ---------------- k0: weight transpose to bf16 [col][k] ----------------
__global__ __launch_bounds__(256) void transpose_k(const float* __restrict__ W,
                                                   const float* __restrict__ R,
                                                   unsigned short* __restrict__ Wt,
                                                   unsigned short* __restrict__ Ut){
  int n = blockIdx.x;        // 0..1535
  int k = threadIdx.x;       // 0..255
  if (n < G3) Wt[n*NU + k] = f2bf(W[k*G3 + n]);
  else        Ut[(n-G3)*NU + k] = f2bf(R[k*G3 + (n-G3)]);
}

// ---------------- k1: projection GEMM ----------------
__global__ __launch_bounds__(256) void proj_k(const float* __restrict__ x,
                                              const unsigned short* __restrict__ Wt,
                                              const float* __restrict__ bias,
                                              uint4* __restrict__ XA4,
                                              uint4* __restrict__ XB4){
  __shared__ short As[4096];
  __shared__ short Bs[4096];
  __shared__ short St[4096];        // [gg 0..3][lane_ 0..63][16]
  const int tid  = threadIdx.x;
  const int lane = tid & 63;
  const int wv   = tid >> 6;
  const int wr   = wv >> 1, wc = wv & 1;
  const int q    = lane >> 4, r16 = lane & 15;
  const int tm   = blockIdx.x;      // time step
  const int bn   = blockIdx.y;      // 0..11 gate-col chunk

  f32x4 acc[2][2];
  #pragma unroll
  for (int a=0;a<2;a++)
    #pragma unroll
    for (int b=0;b<2;b++) acc[a][b] = {0.f,0.f,0.f,0.f};

  const int mA = tid >> 2, kq = tid & 3;
  const int kc32 = kq >> 1, q0 = (kq & 1) * 2;

  for (int kc0 = 0; kc0 < 256; kc0 += 64){
    {
      const float* src = x + (size_t)mA*(2048*256) + (size_t)tm*256 + kc0 + kq*16;
      float4 f0 = *(const float4*)(src);
      float4 f1 = *(const float4*)(src+4);
      float4 f2 = *(const float4*)(src+8);
      float4 f3 = *(const float4*)(src+12);
      *(uint2*)&As[kc32*2048 + q0*512     + mA*8 + 0] = make_uint2(pk2(f0.x,f0.y), pk2(f0.z,f0.w));
      *(uint2*)&As[kc32*2048 + q0*512     + mA*8 + 4] = make_uint2(pk2(f1.x,f1.y), pk2(f1.z,f1.w));
      *(uint2*)&As[kc32*2048 + (q0+1)*512 + mA*8 + 0] = make_uint2(pk2(f2.x,f2.y), pk2(f2.z,f2.w));
      *(uint2*)&As[kc32*2048 + (q0+1)*512 + mA*8 + 4] = make_uint2(pk2(f3.x,f3.y), pk2(f3.z,f3.w));
    }
    {
      const unsigned short* srcB = Wt + (size_t)(bn*64 + mA)*256 + kc0 + kq*16;
      uint4 b0v = *(const uint4*)(srcB);
      uint4 b1v = *(const uint4*)(srcB+8);
      *(uint4*)&Bs[kc32*2048 + q0*512     + mA*8] = b0v;
      *(uint4*)&Bs[kc32*2048 + (q0+1)*512 + mA*8] = b1v;
    }
    __syncthreads();
    #pragma unroll
    for (int kk = 0; kk < 2; kk++){
      bf16x8 av[2], bv[2];
      #pragma unroll
      for (int rt=0; rt<2; rt++)
        av[rt] = *(const bf16x8*)&As[kk*2048 + q*512 + (wr*32+rt*16+r16)*8];
      #pragma unroll
      for (int ct=0; ct<2; ct++)
        bv[ct] = *(const bf16x8*)&Bs[kk*2048 + q*512 + (wc*32+ct*16+r16)*8];
      #pragma unroll
      for (int rt=0; rt<2; rt++)
        #pragma unroll
        for (int ct=0; ct<2; ct++)
          acc[rt][ct] = __builtin_amdgcn_mfma_f32_16x16x32_bf16(av[rt], bv[ct], acc[rt][ct], 0,0,0);
    }
    __syncthreads();
  }

  // epilogue: +bias, stage recurrence-native order in St
  #pragma unroll
  for (int rt=0; rt<2; rt++){
    #pragma unroll
    for (int ct2=0; ct2<2; ct2++){
      int colg = bn*64 + wc*32 + ct2*16 + r16;
      float bb = bias[colg];
      int ct = wc*2 + ct2;                 // gru col-tile 0..3
      #pragma unroll
      for (int i=0;i<4;i++){
        int b = wr*32 + rt*16 + q*4 + i;   // batch
        int gg = b >> 4, lb = b & 15;
        int lane_ = (lb >> 2)*16 + r16, ii = lb & 3;
        St[gg*1024 + lane_*16 + ct*4 + ii] = (short)f2bf(acc[rt][ct2][i] + bb);
      }
    }
  }
  __syncthreads();

  // disjoint coalesced uint4 stores
  const int gate = bn >> 2, w_ = bn & 3;
  #pragma unroll
  for (int it=0; it<2; it++){
    int u = tid + it*256;              // 0..511
    int gg = u >> 7, lane_ = (u >> 1) & 63, half = u & 1;
    uint4 val = *(const uint4*)&St[gg*1024 + lane_*16 + half*8];
    size_t rec = (((size_t)tm*4 + gg)*4 + w_)*64 + lane_;
    if      (gate == 0) XA4[rec*4 + half]     = val;
    else if (gate == 1) XA4[rec*4 + 2 + half] = val;
    else                XB4[rec*2 + half]     = val;
  }
}

// ---------------- k2: recurrence ----------------
__global__ __launch_bounds__(256, 1) void gru_k(const uint4* __restrict__ XA4,
                                                const uint4* __restrict__ XB4,
                                                const unsigned short* __restrict__ Ut,
                                                float* __restrict__ out){
  __shared__ short h_fb[4096];      // h   bf16, frag-order [kc][q][row][8]
  __shared__ short v_fb[4096];      // r*h bf16, same order

  const int tid  = threadIdx.x;
  const int w    = tid >> 6;        // wave 0..3 owns unit cols [w*64, w*64+64)
  const int lane = tid & 63;
  const int q    = lane >> 4, r16 = lane & 15;
  const int g    = blockIdx.x;
  const int b0   = g * 16;

  for (int i = tid; i < 4096; i += 256) h_fb[i] = 0;

  // one-time U load: Uz/Ur -> AGPR (256), Uh -> VGPR (128)
  bf16x8 Uz[4][8], Ur[4][8], Uh[4][8];
  #pragma unroll
  for (int ct=0; ct<4; ct++){
    int col = w*64 + ct*16 + r16;
    #pragma unroll
    for (int kc=0; kc<8; kc++){
      Uz[ct][kc] = *(const bf16x8*)&Ut[(col      )*256 + kc*32 + q*8];
      Ur[ct][kc] = *(const bf16x8*)&Ut[(col + 256)*256 + kc*32 + q*8];
      Uh[ct][kc] = *(const bf16x8*)&Ut[(col + 512)*256 + kc*32 + q*8];
      asm volatile("" : "+a"(Uz[ct][kc]));
      asm volatile("" : "+a"(Ur[ct][kc]));
    }
  }

  float hprev[4][4] = {};
  const uint4* pA = XA4 + ((size_t)(g*4 + w)*64 + lane)*4;
  const uint4* pB = XB4 + ((size_t)(g*4 + w)*64 + lane)*2;
  uint4 xa0 = pA[0], xa1 = pA[1], xa2 = pA[2], xa3 = pA[3];
  uint4 xb0 = pB[0], xb1 = pB[1];
  BAR();

  #pragma unroll 1
  for (int t = 0; t < TB; t++){
    // ---- phase A: z,r = hardsig(x + h@U) over 64 own cols ----
    f32x4 az[4], ar[4];
    #pragma unroll
    for (int ct=0; ct<4; ct++){ az[ct] = {0.f,0.f,0.f,0.f}; ar[ct] = {0.f,0.f,0.f,0.f}; }
    #pragma unroll
    for (int kc=0; kc<8; kc++){
      bf16x8 a = *(const bf16x8*)&h_fb[kc*512 + lane*8];   // lane*16B: conflict-free
      #pragma unroll
      for (int ct=0; ct<4; ct++){
        MFMA_AG(az[ct], a, Uz[ct][kc]);
        MFMA_AG(ar[ct], a, Ur[ct][kc]);
      }
    }
    // MFMA(asm) -> VALU hazard fence (compiler can't see into asm)
    asm volatile("s_nop 7"
      : "+v"(az[0]), "+v"(az[1]), "+v"(az[2]), "+v"(az[3]),
        "+v"(ar[0]), "+v"(ar[1]), "+v"(ar[2]), "+v"(ar[3]));

    unsigned zw[8] = {xa0.x,xa0.y,xa0.z,xa0.w, xa1.x,xa1.y,xa1.z,xa1.w};
    unsigned rw[8] = {xa2.x,xa2.y,xa2.z,xa2.w, xa3.x,xa3.y,xa3.z,xa3.w};
    float zval[4][4];
    #pragma unroll
    for (int ct=0; ct<4; ct++){
      #pragma unroll
      for (int i=0;i<4;i++){
        int s = ct*4 + i;
        float xz = (s&1) ? bfhi(zw[s>>1]) : bflo(zw[s>>1]);
        float xr = (s&1) ? bfhi(rw[s>>1]) : bflo(rw[s>>1]);
        float zf = __builtin_amdgcn_fmed3f(0.2f*(az[ct][i] + xz) + 0.5f, 0.f, 1.f);
        float rf = __builtin_amdgcn_fmed3f(0.2f*(ar[ct][i] + xr) + 0.5f, 0.f, 1.f);
        zval[ct][i] = zf;
        float v = rf * hprev[ct][i];
        v_fb[(w*2+(ct>>1))*512 + ((ct*2+(r16>>3))&3)*128 + (q*4+i)*8 + (r16&7)] = (short)f2bf(v);
      }
    }
    BAR();

    // ---- phase B: hh = tanh(xh + (r*h)@Uh); h = z*h + (1-z)*hh ----
    f32x4 ah[4];
    #pragma unroll
    for (int ct=0; ct<4; ct++) ah[ct] = {0.f,0.f,0.f,0.f};
    #pragma unroll
    for (int kc=0; kc<8; kc++){
      bf16x8 a2 = *(const bf16x8*)&v_fb[kc*512 + lane*8];
      #pragma unroll
      for (int ct=0; ct<4; ct++)
        ah[ct] = __builtin_amdgcn_mfma_f32_16x16x32_bf16(a2, Uh[ct][kc], ah[ct], 0,0,0);
    }
    unsigned hw_[8] = {xb0.x,xb0.y,xb0.z,xb0.w, xb1.x,xb1.y,xb1.z,xb1.w};
    #pragma unroll
    for (int ct=0; ct<4; ct++){
      #pragma unroll
      for (int i=0;i<4;i++){
        int s = ct*4 + i;
        float xh = (s&1) ? bfhi(hw_[s>>1]) : bflo(hw_[s>>1]);
        float pre = __builtin_amdgcn_fmed3f(ah[ct][i] + xh, -15.f, 15.f);
        float e  = __expf(2.f*pre);
        float hh = 1.f - 2.f*__builtin_amdgcn_rcpf(e + 1.f);
        float z  = zval[ct][i];
        float hp = hprev[ct][i];
        float hn = hh + z*(hp - hh);
        hprev[ct][i] = hn;
        h_fb[(w*2+(ct>>1))*512 + ((ct*2+(r16>>3))&3)*128 + (q*4+i)*8 + (r16&7)] = (short)f2bf(hn);
      }
    }
    // prefetch next step's x (stays in flight across BAR: lgkmcnt-only barrier)
    pA += 4096; pB += 2048;
    uint4 na0 = pA[0], na1 = pA[1], na2 = pA[2], na3 = pA[3];
    uint4 nb0 = pB[0], nb1 = pB[1];
    BAR();
    xa0 = na0; xa1 = na1; xa2 = na2; xa3 = na3; xb0 = nb0; xb1 = nb1;
  }

  // h_last from registers
  #pragma unroll
  for (int ct=0; ct<4; ct++)
    #pragma unroll
    for (int i=0;i<4;i++)
      out[(size_t)(b0 + q*4 + i)*256 + w*64 + ct*16 + r16] = hprev[ct][i];
}

extern "C" void kernel_launch(void* const* d_in, const int* in_sizes, int n_in,
                              void* d_out, int out_size, void* d_ws, size_t ws_size,
                              hipStream_t stream) {
  (void)in_sizes; (void)n_in; (void)out_size; (void)ws_size;
  const float* x    = (const float*)d_in[0];
  const float* Wk   = (const float*)d_in[1];
  const float* Rk   = (const float*)d_in[2];
  const float* bias = (const float*)d_in[3];
  float* out = (float*)d_out;

  // XA: 2049 steps (1 pad for prefetch) x 4096 uint4; XB: 2049 x 2048 uint4
  uint4* XA4 = (uint4*)d_ws;
  uint4* XB4 = XA4 + (size_t)2049*4096;
  unsigned short* Wt = (unsigned short*)(XB4 + (size_t)2049*2048);
  unsigned short* Ut = Wt + (size_t)768*256;

  hipLaunchKernelGGL(transpose_k, dim3(1536),    dim3(256), 0, stream, Wk, Rk, Wt, Ut);
  hipLaunchKernelGGL(proj_k,      dim3(2048,12), dim3(256), 0, stream, x, Wt, bias, XA4, XB4);
  hipLaunchKernelGGL(gru_k,       dim3(4),       dim3(256), 0, stream, XA4, XB4, Ut, out);
}